// Round 2
// baseline (8654.473 us; speedup 1.0000x reference)
//
#include <hip/hip_runtime.h>

#define T_SEQ 512
#define NB    256
#define NIN   248
#define NH    1024

typedef __attribute__((ext_vector_type(8))) short          short8;
typedef __attribute__((ext_vector_type(4))) float          f32x4;
typedef __attribute__((ext_vector_type(4))) unsigned int   uint4v;
typedef __attribute__((ext_vector_type(4))) float          float4v;
typedef unsigned long long u64;

#define AS_RELAXED __ATOMIC_RELAXED
#define AS_AGENT   __HIP_MEMORY_SCOPE_AGENT

__device__ __forceinline__ unsigned short f2bf(float f){
  unsigned int u = __float_as_uint(f);
  u += 0x7FFFu + ((u >> 16) & 1u);     // RNE
  return (unsigned short)(u >> 16);
}
__device__ __forceinline__ unsigned pk2(float lo, float hi){
  return (unsigned)f2bf(lo) | ((unsigned)f2bf(hi) << 16);
}
__device__ __forceinline__ float tanh_fast(float v){
  float e = __expf(2.0f * v);          // overflow -> inf -> tanh -> 1 (safe)
  return 1.0f - 2.0f / (e + 1.0f);
}

// Barrier WITHOUT the vmcnt(0) drain __syncthreads carries: only LDS
// visibility (lgkmcnt) is required across the stage->mfma edge; global
// loads stay in flight across it (counted-wait pattern).
__device__ __forceinline__ void barrier_lds(){
  asm volatile("s_waitcnt lgkmcnt(0)" ::: "memory");
  __builtin_amdgcn_s_barrier();
  __builtin_amdgcn_sched_barrier(0);
}

// Per-wave flag wait: lanes 0..63 each watch one producer-wave flag.
// 'spec' is a speculatively preloaded value (issued long before) so the
// steady-state cost is ~0; fallback is a relaxed sc1 spin.
__device__ __forceinline__ void wait_flags(unsigned spec, const unsigned* fl,
                                           int l, unsigned tgt){
  if (__all((int)(spec >= tgt))) return;
  unsigned v;
  do {
    __builtin_amdgcn_s_sleep(1);
    v = __hip_atomic_load(&fl[l], AS_RELAXED, AS_AGENT);
  } while (!__all((int)(v >= tgt)));
}

// DUAL-STREAM persistent RNN scan. 128 WGs = 8 pairs x 16 jg. Each WG owns
// TWO batch-groups (A: 16 rows, B: 16 rows) sharing one resident W-slice.
// A's exchange latency (store-ack -> flag -> propagate -> reload) hides
// under B's stage+MFMA+tanh and vice versa.
//
// Flags are per PRODUCER WAVE: flags[bg][jg*4+wv] = 1 + latest h index that
// wave stored. Publish needs only the wave's own vmcnt(0) (no WG drain).
// Ping-pong safety: a wave stores h[t+1] (overwriting h[t-1]) only after
// having observed, in iteration t-1, all flags >= t+1 - i.e. every peer
// STORED h[t], which in program order follows their stage-consumption of
// h[t-1], so the loads of h[t-1] had completed. Flag->data visibility:
// data stores are relaxed agent-scope (write-through, acked at MALL);
// vmcnt(0) precedes the flag store; a consumer that observes the flag
// observes the data through the same coherence point.
__launch_bounds__(256, 1)
__global__ void rnn_scan_kernel(const float* __restrict__ x,
                                const float* __restrict__ W_ih,
                                const float* __restrict__ b_ih,
                                const float* __restrict__ W_hh,
                                const float* __restrict__ b_hh,
                                const float* __restrict__ W_out,
                                unsigned short* __restrict__ hbuf,
                                float* __restrict__ z,
                                unsigned int* __restrict__ bar)
{
  __shared__ alignas(16) unsigned short h_fragA[2048 * 8]; // 32 KB
  __shared__ alignas(16) unsigned short h_fragB[2048 * 8]; // 32 KB
  __shared__ alignas(16) unsigned short x_fragA[512 * 8];  //  8 KB
  __shared__ alignas(16) unsigned short x_fragB[512 * 8];  //  8 KB
  __shared__ alignas(8)  unsigned short h_out[4 * 256];    //  2 KB (per-wave)
  __shared__ float z_histA[T_SEQ * 16];                    // 32 KB
  __shared__ float z_histB[T_SEQ * 16];                    // 32 KB

  const int tid    = threadIdx.x;
  const int wg     = blockIdx.x;
  const int pairId = wg & 7;
  const int jg     = wg >> 3;
  const int b_baseA = pairId * 32;
  const int b_baseB = pairId * 32 + 16;
  const int l      = tid & 63;
  const int wv     = tid >> 6;
  const int n      = l & 15;
  const int quad   = l >> 4;
  const int j      = jg * 64 + wv * 16 + n;

  unsigned short* h0 = hbuf;
  unsigned short* h1 = hbuf + (size_t)NB * NH;
  unsigned int* flagsA = bar + pairId * 128;
  unsigned int* flagsB = bar + pairId * 128 + 64;

  // ---- resident B fragments: W_hh^T / W_ih^T slices (bf16) in VGPRs ----
  short8 whh[32];
  #pragma unroll
  for (int kt = 0; kt < 32; ++kt){
    const float* p = W_hh + (size_t)j * NH + kt * 32 + quad * 8;
    float4v a = *(const float4v*)p;
    float4v b = *(const float4v*)(p + 4);
    short8 v;
    v[0]=(short)f2bf(a[0]); v[1]=(short)f2bf(a[1]); v[2]=(short)f2bf(a[2]); v[3]=(short)f2bf(a[3]);
    v[4]=(short)f2bf(b[0]); v[5]=(short)f2bf(b[1]); v[6]=(short)f2bf(b[2]); v[7]=(short)f2bf(b[3]);
    whh[kt] = v;
  }
  short8 wih[8];
  #pragma unroll
  for (int kt = 0; kt < 8; ++kt){
    short8 v = {0,0,0,0,0,0,0,0};
    if (!(kt == 7 && quad == 3)){            // k in [248,256) -> zero pad
      const float* p = W_ih + (size_t)j * NIN + kt * 32 + quad * 8;
      float4v a = *(const float4v*)p;
      float4v b = *(const float4v*)(p + 4);
      v[0]=(short)f2bf(a[0]); v[1]=(short)f2bf(a[1]); v[2]=(short)f2bf(a[2]); v[3]=(short)f2bf(a[3]);
      v[4]=(short)f2bf(b[0]); v[5]=(short)f2bf(b[1]); v[6]=(short)f2bf(b[2]); v[7]=(short)f2bf(b[3]);
    }
    wih[kt] = v;
  }
  const float bias  = b_ih[j] + b_hh[j];
  const float woutj = W_out[j];

  // ---- init: z_hist, h0 slices (both bgs), z global slices ----
  #pragma unroll
  for (int i = 0; i < 32; ++i){
    z_histA[tid + i * 256] = 0.f;
    z_histB[tid + i * 256] = 0.f;
  }
  {
    int r = l >> 2, c = (l & 3) * 4;
    size_t col = (size_t)jg * 64 + wv * 16 + c;
    __hip_atomic_store((u64*)&h0[(size_t)(b_baseA + r) * NH + col], 0ull, AS_RELAXED, AS_AGENT);
    __hip_atomic_store((u64*)&h0[(size_t)(b_baseB + r) * NH + col], 0ull, AS_RELAXED, AS_AGENT);
    int tt = jg * 32 + (tid >> 3);
    int bb = (tid & 7) * 2;
    __hip_atomic_store(&z[(size_t)tt * NB + b_baseA + bb],     0.f, AS_RELAXED, AS_AGENT);
    __hip_atomic_store(&z[(size_t)tt * NB + b_baseA + bb + 1], 0.f, AS_RELAXED, AS_AGENT);
    __hip_atomic_store(&z[(size_t)tt * NB + b_baseB + bb],     0.f, AS_RELAXED, AS_AGENT);
    __hip_atomic_store(&z[(size_t)tt * NB + b_baseB + bb + 1], 0.f, AS_RELAXED, AS_AGENT);
  }
  asm volatile("s_waitcnt vmcnt(0)" ::: "memory");
  if (l == 0){
    __hip_atomic_store(&flagsA[jg * 4 + wv], 1u, AS_RELAXED, AS_AGENT);
    __hip_atomic_store(&flagsB[jg * 4 + wv], 1u, AS_RELAXED, AS_AGENT);
  }

  // ---- x slots ----
  const int xslot_kt[2] = { tid >> 6, (tid + 256) >> 6 };
  const int xslot_l2[2] = { tid & 63, tid & 63 };
  bool xvalid[2];
  #pragma unroll
  for (int i = 0; i < 2; ++i)
    xvalid[i] = !(xslot_kt[i] == 7 && (xslot_l2[i] >> 4) == 3);

  float4v xrA[2][2], xrB[2][2];
  u64 hwA0[8], hwA1[8], hwB0[8], hwB1[8];
  unsigned fA = 0, fB = 0;

#define XPREF(XR, BBASE, TN)                                               \
  _Pragma("unroll")                                                        \
  for (int i = 0; i < 2; ++i){                                             \
    if (xvalid[i]){                                                        \
      int kt = xslot_kt[i], l2 = xslot_l2[i];                              \
      int b = (BBASE) + (l2 & 15), k = kt * 32 + (l2 >> 4) * 8;            \
      const float* p = x + ((size_t)(TN) * NB + b) * NIN + k;              \
      XR[i][0] = *(const float4v*)p;                                       \
      XR[i][1] = *(const float4v*)(p + 4);                                 \
    }                                                                      \
  }

#define STAGE_H(HF, HW0, HW1)                                              \
  _Pragma("unroll")                                                        \
  for (int i = 0; i < 8; ++i){                                             \
    u64* dst = (u64*)&HF[(tid + i * 256) * 8];                             \
    dst[0] = HW0[i]; dst[1] = HW1[i];                                      \
  }

#define STAGE_X(XF, XR)                                                    \
  _Pragma("unroll")                                                        \
  for (int i = 0; i < 2; ++i){                                             \
    uint4v v = {0u,0u,0u,0u};                                              \
    if (xvalid[i]){                                                        \
      v[0] = pk2(XR[i][0][0], XR[i][0][1]);                                \
      v[1] = pk2(XR[i][0][2], XR[i][0][3]);                                \
      v[2] = pk2(XR[i][1][0], XR[i][1][1]);                                \
      v[3] = pk2(XR[i][1][2], XR[i][1][3]);                                \
    }                                                                      \
    *(uint4v*)&XF[(tid + i * 256) * 8] = v;                                \
  }

#define LOAD_H(HW0, HW1, HSRC, BBASE)                                      \
  _Pragma("unroll")                                                        \
  for (int i = 0; i < 8; ++i){                                             \
    int slot = tid + i * 256;                                              \
    int kt = slot >> 6, l2 = slot & 63;                                    \
    const u64* src = (const u64*)((HSRC)                                   \
        + (size_t)((BBASE) + (l2 & 15)) * NH + kt * 32 + (l2 >> 4) * 8);   \
    HW0[i] = __hip_atomic_load(src,     AS_RELAXED, AS_AGENT);             \
    HW1[i] = __hip_atomic_load(src + 1, AS_RELAXED, AS_AGENT);             \
  }

#define MFMA_TILE(HF, XF, A0, A1, A2, A3)                                  \
  _Pragma("unroll")                                                        \
  for (int kt = 0; kt < 32; kt += 4){                                      \
    short8 q0 = *(const short8*)&HF[((kt + 0) * 64 + l) * 8];              \
    short8 q1 = *(const short8*)&HF[((kt + 1) * 64 + l) * 8];              \
    short8 q2 = *(const short8*)&HF[((kt + 2) * 64 + l) * 8];              \
    short8 q3 = *(const short8*)&HF[((kt + 3) * 64 + l) * 8];              \
    A0 = __builtin_amdgcn_mfma_f32_16x16x32_bf16(q0, whh[kt + 0], A0, 0, 0, 0); \
    A1 = __builtin_amdgcn_mfma_f32_16x16x32_bf16(q1, whh[kt + 1], A1, 0, 0, 0); \
    A2 = __builtin_amdgcn_mfma_f32_16x16x32_bf16(q2, whh[kt + 2], A2, 0, 0, 0); \
    A3 = __builtin_amdgcn_mfma_f32_16x16x32_bf16(q3, whh[kt + 3], A3, 0, 0, 0); \
  }                                                                        \
  _Pragma("unroll")                                                        \
  for (int kt = 0; kt < 8; kt += 4){                                       \
    short8 q0 = *(const short8*)&XF[((kt + 0) * 64 + l) * 8];              \
    short8 q1 = *(const short8*)&XF[((kt + 1) * 64 + l) * 8];              \
    short8 q2 = *(const short8*)&XF[((kt + 2) * 64 + l) * 8];              \
    short8 q3 = *(const short8*)&XF[((kt + 3) * 64 + l) * 8];              \
    A0 = __builtin_amdgcn_mfma_f32_16x16x32_bf16(q0, wih[kt + 0], A0, 0, 0, 0); \
    A1 = __builtin_amdgcn_mfma_f32_16x16x32_bf16(q1, wih[kt + 1], A1, 0, 0, 0); \
    A2 = __builtin_amdgcn_mfma_f32_16x16x32_bf16(q2, wih[kt + 2], A2, 0, 0, 0); \
    A3 = __builtin_amdgcn_mfma_f32_16x16x32_bf16(q3, wih[kt + 3], A3, 0, 0, 0); \
  }

#define FINISH(A0, A1, A2, A3, ZH, BBASE, FLAGS, TPUB)                     \
  {                                                                        \
    float sv[4];                                                           \
    _Pragma("unroll")                                                      \
    for (int i = 0; i < 4; ++i){                                           \
      float hvv = tanh_fast(A0[i] + A1[i] + A2[i] + A3[i]);                \
      h_out[wv * 256 + (quad * 4 + i) * 16 + n] = f2bf(hvv);               \
      sv[i] = hvv * woutj;                                                 \
    }                                                                      \
    _Pragma("unroll")                                                      \
    for (int m = 1; m < 16; m <<= 1){                                      \
      _Pragma("unroll")                                                    \
      for (int i = 0; i < 4; ++i) sv[i] += __shfl_xor(sv[i], m, 64);       \
    }                                                                      \
    if (n == 0){                                                           \
      _Pragma("unroll")                                                    \
      for (int i = 0; i < 4; ++i)                                          \
        atomicAdd(&ZH[t * 16 + quad * 4 + i], sv[i]);                      \
    }                                                                      \
    {                                                                      \
      int r = l >> 2, c = (l & 3) * 4;                                     \
      u64 v = *(const u64*)&h_out[wv * 256 + r * 16 + c];                  \
      __hip_atomic_store((u64*)&hn[(size_t)((BBASE) + r) * NH              \
                         + jg * 64 + wv * 16 + c], v, AS_RELAXED, AS_AGENT); \
    }                                                                      \
    asm volatile("s_waitcnt vmcnt(0)" ::: "memory");                       \
    if (l == 0)                                                            \
      __hip_atomic_store(&FLAGS[jg * 4 + wv], (unsigned)(TPUB),            \
                         AS_RELAXED, AS_AGENT);                            \
  }

  // ---- prologue: wait peers' init, preload A stream, spec B flags ----
  wait_flags(0u, flagsA, l, 1u);
  LOAD_H(hwA0, hwA1, h0, b_baseA);
  fB = __hip_atomic_load(&flagsB[l], AS_RELAXED, AS_AGENT);
  XPREF(xrA, b_baseA, 0);
  XPREF(xrB, b_baseB, 0);

  for (int t = 0; t < T_SEQ; ++t){
    const unsigned short* hp = (t & 1) ? h1 : h0;
    unsigned short*       hn = (t & 1) ? h0 : h1;
    const int tn = (t + 1 < T_SEQ) ? t + 1 : t;

    // ================= A half =================
    STAGE_H(h_fragA, hwA0, hwA1);
    wait_flags(fB, flagsB, l, (unsigned)(t + 1));   // h_B[t] ready
    LOAD_H(hwB0, hwB1, hp, b_baseB);                // in flight under mfmaA
    STAGE_X(x_fragA, xrA);
    XPREF(xrA, b_baseA, tn);
    barrier_lds();
    f32x4 a0 = {bias, bias, bias, bias};
    f32x4 a1 = {0.f, 0.f, 0.f, 0.f};
    f32x4 a2 = {0.f, 0.f, 0.f, 0.f};
    f32x4 a3 = {0.f, 0.f, 0.f, 0.f};
    MFMA_TILE(h_fragA, x_fragA, a0, a1, a2, a3);
    FINISH(a0, a1, a2, a3, z_histA, b_baseA, flagsA, t + 2);
    fA = __hip_atomic_load(&flagsA[l], AS_RELAXED, AS_AGENT);  // spec for checkA

    // ================= B half =================
    STAGE_H(h_fragB, hwB0, hwB1);
    wait_flags(fA, flagsA, l, (unsigned)(t + 2));   // h_A[t+1] ready
    LOAD_H(hwA0, hwA1, hn, b_baseA);                // in flight under mfmaB
    STAGE_X(x_fragB, xrB);
    XPREF(xrB, b_baseB, tn);
    barrier_lds();
    f32x4 b0 = {bias, bias, bias, bias};
    f32x4 b1 = {0.f, 0.f, 0.f, 0.f};
    f32x4 b2 = {0.f, 0.f, 0.f, 0.f};
    f32x4 b3 = {0.f, 0.f, 0.f, 0.f};
    MFMA_TILE(h_fragB, x_fragB, b0, b1, b2, b3);
    FINISH(b0, b1, b2, b3, z_histB, b_baseB, flagsB, t + 2);
    fB = __hip_atomic_load(&flagsB[l], AS_RELAXED, AS_AGENT);  // spec for next checkB
  }

  // ---- bulk z flush (off the critical path) ----
  __syncthreads();
  #pragma unroll
  for (int i = 0; i < 32; ++i){
    int idx = tid + i * 256;
    int tt = idx >> 4, bb = idx & 15;
    atomicAdd(&z[(size_t)tt * NB + b_baseA + bb], z_histA[idx]);
    atomicAdd(&z[(size_t)tt * NB + b_baseB + bb], z_histB[idx]);
  }

#undef XPREF
#undef STAGE_H
#undef STAGE_X
#undef LOAD_H
#undef MFMA_TILE
#undef FINISH
}

// o_t = sigmoid(z_t + b_out + w_r*o_{t-1} + b_r), o_0 = sigmoid(z_0 + b_out).
// 256 independent chains. Output (B, T) row-major.
__global__ void out_scan_kernel(const float* __restrict__ z,
                                const float* __restrict__ b_out,
                                const float* __restrict__ w_r,
                                const float* __restrict__ b_r,
                                float* __restrict__ out)
{
  int b = threadIdx.x;
  float bo = b_out[0], wr = w_r[0], br = b_r[0];
  float o = 0.f;
  for (int t = 0; t < T_SEQ; ++t){
    float pre = z[(size_t)t * NB + b] + bo;
    if (t > 0) pre += wr * o + br;
    o = 1.0f / (1.0f + __expf(-pre));
    out[(size_t)b * T_SEQ + t] = o;
  }
}

extern "C" void kernel_launch(void* const* d_in, const int* in_sizes, int n_in,
                              void* d_out, int out_size, void* d_ws, size_t ws_size,
                              hipStream_t stream)
{
  (void)in_sizes; (void)n_in; (void)out_size; (void)ws_size;
  const float* x     = (const float*)d_in[0];
  const float* W_ih  = (const float*)d_in[1];
  const float* b_ih  = (const float*)d_in[2];
  const float* W_hh  = (const float*)d_in[3];
  const float* b_hh  = (const float*)d_in[4];
  const float* W_out = (const float*)d_in[5];
  const float* b_out = (const float*)d_in[6];
  const float* w_r   = (const float*)d_in[7];
  const float* b_r   = (const float*)d_in[8];
  float* out = (float*)d_out;

  // ws: h ping-pong (2 x 512 KB bf16) | z (512 KB fp32) | flags (4 KB)
  unsigned short* hbuf = (unsigned short*)d_ws;
  float* z = (float*)((char*)d_ws + 2 * (size_t)NB * NH * sizeof(unsigned short));
  unsigned int* bar = (unsigned int*)((char*)d_ws
                        + 2 * (size_t)NB * NH * sizeof(unsigned short)
                        + (size_t)T_SEQ * NB * sizeof(float));

  hipMemsetAsync(bar, 0, 8 * 128 * sizeof(unsigned int), stream);

  rnn_scan_kernel<<<dim3(128), dim3(256), 0, stream>>>(
      x, W_ih, b_ih, W_hh, b_hh, W_out, hbuf, z, bar);

  out_scan_kernel<<<dim3(1), dim3(256), 0, stream>>>(z, b_out, w_r, b_r, out);
}

// Round 3
// 2436.136 us; speedup vs baseline: 3.5525x; 3.5525x over previous
//
#include <hip/hip_runtime.h>

#define T_SEQ 512
#define NB    256
#define NIN   248
#define NH    1024

typedef __attribute__((ext_vector_type(8))) short          short8;
typedef __attribute__((ext_vector_type(4))) float          f32x4;
typedef __attribute__((ext_vector_type(4))) unsigned int   uint4v;
typedef __attribute__((ext_vector_type(4))) float          float4v;
typedef unsigned long long u64;

#define AS_RELAXED __ATOMIC_RELAXED
#define AS_AGENT   __HIP_MEMORY_SCOPE_AGENT

__device__ __forceinline__ unsigned short f2bf(float f){
  unsigned int u = __float_as_uint(f);
  u += 0x7FFFu + ((u >> 16) & 1u);     // RNE
  return (unsigned short)(u >> 16);
}
__device__ __forceinline__ unsigned pk2(float lo, float hi){
  return (unsigned)f2bf(lo) | ((unsigned)f2bf(hi) << 16);
}
__device__ __forceinline__ float tanh_fast(float v){
  float e = __expf(2.0f * v);          // overflow -> inf -> tanh -> 1 (safe)
  return 1.0f - 2.0f / (e + 1.0f);
}

// Barrier WITHOUT the vmcnt(0) drain __syncthreads carries: only LDS
// visibility is needed across the stage->mfma edge; global loads stay in
// flight across it. asm "memory" clobber = compiler fence; sched_barrier
// pins instruction movement.
__device__ __forceinline__ void barrier_lds(){
  asm volatile("s_waitcnt lgkmcnt(0)" ::: "memory");
  __builtin_amdgcn_s_barrier();
  __builtin_amdgcn_sched_barrier(0);
}

// Single-stream persistent RNN scan (R1 structure, verified @2047us) with:
//  - per-wave flags: flags[bg][jg*4+wv] = 1 + latest h index that WAVE
//    stored; publish after the wave's OWN vmcnt(0) only (8B store ack).
//    Consumers poll all 64 producer-wave flags with one 64-lane load.
//  - speculative flag preload at end of step t-1 -> loop-top wait ~free.
//  - two-phase stage/MFMA: stage slots i=0..3 (== kt 0..15 exactly),
//    barrier, MFMA kt0..15 while loads 8..15 fly, stage i=4..7 (disjoint
//    LDS range), barrier, MFMA kt16..31 + x.
//  - z-reduce and x-prefetch moved AFTER the publish (off critical path);
//    at the pre-publish vmcnt(0) the only outstanding VMEM is the h store.
//
// Ping-pong / LDS-reuse safety: the loop-top wait (flags >= t+1, published
// at end of step t-1 as value t+1... published value at end of step T is
// T+2) guarantees every producer wave -- including our own WG's waves --
// finished step t-1 entirely: their h[t-1]-buffer reads and h[t] stores
// are complete before we overwrite h_frag/x_frag or the h[t-1] buffer.
__launch_bounds__(256, 1)
__global__ void rnn_scan_kernel(const float* __restrict__ x,
                                const float* __restrict__ W_ih,
                                const float* __restrict__ b_ih,
                                const float* __restrict__ W_hh,
                                const float* __restrict__ b_hh,
                                const float* __restrict__ W_out,
                                unsigned short* __restrict__ hbuf,
                                float* __restrict__ z,
                                unsigned int* __restrict__ bar)
{
  __shared__ alignas(16) unsigned short h_frag[2048 * 8]; // 32 KB A-fragments
  __shared__ alignas(16) unsigned short x_frag[512 * 8];  //  8 KB x-fragments
  __shared__ alignas(8)  unsigned short h_out[4 * 256];   //  2 KB per-wave transpose
  __shared__ float z_hist[T_SEQ * 16];                    // 32 KB deferred z partials

  const int tid    = threadIdx.x;
  const int wg     = blockIdx.x;
  const int r16    = wg & 15;
  const int bg     = (r16 & 7) * 2 + (r16 >> 3);  // same-XCD grouping heuristic
  const int jg     = wg >> 4;
  const int b_base = bg * 16;
  const int l      = tid & 63;
  const int wv     = tid >> 6;
  const int n      = l & 15;
  const int quad   = l >> 4;
  const int j      = jg * 64 + wv * 16 + n;

  unsigned short* h0 = hbuf;
  unsigned short* h1 = hbuf + (size_t)NB * NH;
  unsigned int* flags = bar + bg * 64;        // 64 flags (256 B) per batch-group

  // ---- resident B fragments: W_hh^T / W_ih^T slices (bf16) in VGPRs ----
  short8 whh[32];
  #pragma unroll
  for (int kt = 0; kt < 32; ++kt){
    const float* p = W_hh + (size_t)j * NH + kt * 32 + quad * 8;
    float4v a = *(const float4v*)p;
    float4v b = *(const float4v*)(p + 4);
    short8 v;
    v[0]=(short)f2bf(a[0]); v[1]=(short)f2bf(a[1]); v[2]=(short)f2bf(a[2]); v[3]=(short)f2bf(a[3]);
    v[4]=(short)f2bf(b[0]); v[5]=(short)f2bf(b[1]); v[6]=(short)f2bf(b[2]); v[7]=(short)f2bf(b[3]);
    whh[kt] = v;
  }
  short8 wih[8];
  #pragma unroll
  for (int kt = 0; kt < 8; ++kt){
    short8 v = {0,0,0,0,0,0,0,0};
    if (!(kt == 7 && quad == 3)){            // k in [248,256) -> zero pad
      const float* p = W_ih + (size_t)j * NIN + kt * 32 + quad * 8;
      float4v a = *(const float4v*)p;
      float4v b = *(const float4v*)(p + 4);
      v[0]=(short)f2bf(a[0]); v[1]=(short)f2bf(a[1]); v[2]=(short)f2bf(a[2]); v[3]=(short)f2bf(a[3]);
      v[4]=(short)f2bf(b[0]); v[5]=(short)f2bf(b[1]); v[6]=(short)f2bf(b[2]); v[7]=(short)f2bf(b[3]);
    }
    wih[kt] = v;
  }
  const float bias  = b_ih[j] + b_hh[j];
  const float woutj = W_out[j];

  // ---- init: z_hist = 0, h0 slice = 0, z global slice = 0 ----
  #pragma unroll
  for (int i = 0; i < 32; ++i) z_hist[tid + i * 256] = 0.f;
  {
    int r = tid >> 4, c = (tid & 15) * 4;
    __hip_atomic_store((u64*)&h0[(size_t)(b_base + r) * NH + jg * 64 + c],
                       0ull, AS_RELAXED, AS_AGENT);
    int tt = jg * 32 + (tid >> 3);
    int bb = (tid & 7) * 2;
    __hip_atomic_store(&z[(size_t)tt * NB + b_base + bb],     0.f, AS_RELAXED, AS_AGENT);
    __hip_atomic_store(&z[(size_t)tt * NB + b_base + bb + 1], 0.f, AS_RELAXED, AS_AGENT);
  }
  asm volatile("s_waitcnt vmcnt(0)" ::: "memory");
  if (l == 0)
    __hip_atomic_store(&flags[jg * 4 + wv], 1u, AS_RELAXED, AS_AGENT);

  // ---- x prefetch slots (t=0) ----
  const int xslot_kt[2] = { tid >> 6, (tid + 256) >> 6 };
  const int xslot_l2[2] = { tid & 63, tid & 63 };
  float4v xr[2][2];
  bool    xvalid[2];
  #pragma unroll
  for (int i = 0; i < 2; ++i){
    int kt = xslot_kt[i], l2 = xslot_l2[i];
    int b = b_base + (l2 & 15), k = kt * 32 + (l2 >> 4) * 8;
    xvalid[i] = !(kt == 7 && (l2 >> 4) == 3);
    if (xvalid[i]){
      const float* p = x + ((size_t)0 * NB + b) * NIN + k;
      xr[i][0] = *(const float4v*)p;
      xr[i][1] = *(const float4v*)(p + 4);
    }
  }

  unsigned spec = 0;

  for (int t = 0; t < T_SEQ; ++t){
    const unsigned short* hp = (t & 1) ? h1 : h0;
    unsigned short*       hn = (t & 1) ? h0 : h1;
    const int tn = (t + 1 < T_SEQ) ? t + 1 : t;

    // ---- wait for h[t] (speculative preload usually satisfies) ----
    if (!__all((int)(spec >= (unsigned)(t + 1)))){
      unsigned v;
      do {
        __builtin_amdgcn_s_sleep(1);
        v = __hip_atomic_load(&flags[l], AS_RELAXED, AS_AGENT);
      } while (!__all((int)(v >= (unsigned)(t + 1))));
    }
    __builtin_amdgcn_sched_barrier(0);

    // ---- issue ALL 16 coherent h loads (max MLP) ----
    u64 hw0[8], hw1[8];
    #pragma unroll
    for (int i = 0; i < 8; ++i){
      int slot = tid + i * 256;
      int kt = slot >> 6, l2 = slot & 63;
      const u64* src = (const u64*)(hp
          + (size_t)(b_base + (l2 & 15)) * NH + kt * 32 + (l2 >> 4) * 8);
      hw0[i] = __hip_atomic_load(src,     AS_RELAXED, AS_AGENT);
      hw1[i] = __hip_atomic_load(src + 1, AS_RELAXED, AS_AGENT);
    }
    // x stage from prefetched regs (no dependence on h loads)
    #pragma unroll
    for (int i = 0; i < 2; ++i){
      uint4v v = {0u,0u,0u,0u};
      if (xvalid[i]){
        v[0] = pk2(xr[i][0][0], xr[i][0][1]);
        v[1] = pk2(xr[i][0][2], xr[i][0][3]);
        v[2] = pk2(xr[i][1][0], xr[i][1][1]);
        v[3] = pk2(xr[i][1][2], xr[i][1][3]);
      }
      *(uint4v*)&x_frag[(tid + i * 256) * 8] = v;
    }
    // phase-1 h stage: slots i=0..3 == kt 0..15 (consumes loads 0..7)
    #pragma unroll
    for (int i = 0; i < 4; ++i){
      u64* dst = (u64*)&h_frag[(tid + i * 256) * 8];
      dst[0] = hw0[i]; dst[1] = hw1[i];
    }
    barrier_lds();

    // ---- phase A MFMA: kt 0..15 (loads 8..15 still in flight) ----
    f32x4 a0 = {bias, bias, bias, bias};
    f32x4 a1 = {0.f, 0.f, 0.f, 0.f};
    f32x4 a2 = {0.f, 0.f, 0.f, 0.f};
    f32x4 a3 = {0.f, 0.f, 0.f, 0.f};
    #pragma unroll
    for (int kt = 0; kt < 16; kt += 4){
      short8 q0 = *(const short8*)&h_frag[((kt + 0) * 64 + l) * 8];
      short8 q1 = *(const short8*)&h_frag[((kt + 1) * 64 + l) * 8];
      short8 q2 = *(const short8*)&h_frag[((kt + 2) * 64 + l) * 8];
      short8 q3 = *(const short8*)&h_frag[((kt + 3) * 64 + l) * 8];
      a0 = __builtin_amdgcn_mfma_f32_16x16x32_bf16(q0, whh[kt + 0], a0, 0, 0, 0);
      a1 = __builtin_amdgcn_mfma_f32_16x16x32_bf16(q1, whh[kt + 1], a1, 0, 0, 0);
      a2 = __builtin_amdgcn_mfma_f32_16x16x32_bf16(q2, whh[kt + 2], a2, 0, 0, 0);
      a3 = __builtin_amdgcn_mfma_f32_16x16x32_bf16(q3, whh[kt + 3], a3, 0, 0, 0);
    }
    __builtin_amdgcn_sched_barrier(0);

    // phase-2 h stage: slots i=4..7 == kt 16..31 (disjoint from phase-A reads)
    #pragma unroll
    for (int i = 4; i < 8; ++i){
      u64* dst = (u64*)&h_frag[(tid + i * 256) * 8];
      dst[0] = hw0[i]; dst[1] = hw1[i];
    }
    barrier_lds();

    // ---- phase B MFMA: kt 16..31 + x kt 0..7 ----
    #pragma unroll
    for (int kt = 16; kt < 32; kt += 4){
      short8 q0 = *(const short8*)&h_frag[((kt + 0) * 64 + l) * 8];
      short8 q1 = *(const short8*)&h_frag[((kt + 1) * 64 + l) * 8];
      short8 q2 = *(const short8*)&h_frag[((kt + 2) * 64 + l) * 8];
      short8 q3 = *(const short8*)&h_frag[((kt + 3) * 64 + l) * 8];
      a0 = __builtin_amdgcn_mfma_f32_16x16x32_bf16(q0, whh[kt + 0], a0, 0, 0, 0);
      a1 = __builtin_amdgcn_mfma_f32_16x16x32_bf16(q1, whh[kt + 1], a1, 0, 0, 0);
      a2 = __builtin_amdgcn_mfma_f32_16x16x32_bf16(q2, whh[kt + 2], a2, 0, 0, 0);
      a3 = __builtin_amdgcn_mfma_f32_16x16x32_bf16(q3, whh[kt + 3], a3, 0, 0, 0);
    }
    #pragma unroll
    for (int kt = 0; kt < 8; kt += 4){
      short8 q0 = *(const short8*)&x_frag[((kt + 0) * 64 + l) * 8];
      short8 q1 = *(const short8*)&x_frag[((kt + 1) * 64 + l) * 8];
      short8 q2 = *(const short8*)&x_frag[((kt + 2) * 64 + l) * 8];
      short8 q3 = *(const short8*)&x_frag[((kt + 3) * 64 + l) * 8];
      a0 = __builtin_amdgcn_mfma_f32_16x16x32_bf16(q0, wih[kt + 0], a0, 0, 0, 0);
      a1 = __builtin_amdgcn_mfma_f32_16x16x32_bf16(q1, wih[kt + 1], a1, 0, 0, 0);
      a2 = __builtin_amdgcn_mfma_f32_16x16x32_bf16(q2, wih[kt + 2], a2, 0, 0, 0);
      a3 = __builtin_amdgcn_mfma_f32_16x16x32_bf16(q3, wih[kt + 3], a3, 0, 0, 0);
    }

    // ---- finish: tanh -> per-wave LDS transpose -> 8B store -> publish ----
    float hv[4];
    #pragma unroll
    for (int i = 0; i < 4; ++i){
      hv[i] = tanh_fast(a0[i] + a1[i] + a2[i] + a3[i]);
      // C/D layout: row(b) = quad*4 + i, col(j) = n; wave-private region
      h_out[wv * 256 + (quad * 4 + i) * 16 + n] = f2bf(hv[i]);
    }
    {
      int r = l >> 2, c = (l & 3) * 4;   // wave-local 16x16 tile transpose
      u64 v = *(const u64*)&h_out[wv * 256 + r * 16 + c];
      __hip_atomic_store((u64*)&hn[(size_t)(b_base + r) * NH
                         + jg * 64 + wv * 16 + c], v, AS_RELAXED, AS_AGENT);
    }
    asm volatile("s_waitcnt vmcnt(0)" ::: "memory");   // only the h store pending
    if (l == 0)
      __hip_atomic_store(&flags[jg * 4 + wv], (unsigned)(t + 2),
                         AS_RELAXED, AS_AGENT);
    __builtin_amdgcn_sched_barrier(0);

    // ---- off critical path: x prefetch t+1, z reduce, spec reload ----
    #pragma unroll
    for (int i = 0; i < 2; ++i){
      if (xvalid[i]){
        int kt = xslot_kt[i], l2 = xslot_l2[i];
        int b = b_base + (l2 & 15), k = kt * 32 + (l2 >> 4) * 8;
        const float* p = x + ((size_t)tn * NB + b) * NIN + k;
        xr[i][0] = *(const float4v*)p;
        xr[i][1] = *(const float4v*)(p + 4);
      }
    }
    float sv[4];
    #pragma unroll
    for (int i = 0; i < 4; ++i) sv[i] = hv[i] * woutj;
    #pragma unroll
    for (int m = 1; m < 16; m <<= 1){
      #pragma unroll
      for (int i = 0; i < 4; ++i) sv[i] += __shfl_xor(sv[i], m, 64);
    }
    if (n == 0){
      #pragma unroll
      for (int i = 0; i < 4; ++i) atomicAdd(&z_hist[t * 16 + quad * 4 + i], sv[i]);
    }
    spec = __hip_atomic_load(&flags[l], AS_RELAXED, AS_AGENT);
  }

  // ---- bulk z flush (off the critical path) ----
  __syncthreads();
  #pragma unroll
  for (int i = 0; i < 32; ++i){
    int idx = tid + i * 256;
    int tt = idx >> 4, bb = idx & 15;
    atomicAdd(&z[(size_t)tt * NB + b_base + bb], z_hist[idx]);
  }
}

// o_t = sigmoid(z_t + b_out + w_r*o_{t-1} + b_r), o_0 = sigmoid(z_0 + b_out).
// 256 independent chains. Output (B, T) row-major.
__global__ void out_scan_kernel(const float* __restrict__ z,
                                const float* __restrict__ b_out,
                                const float* __restrict__ w_r,
                                const float* __restrict__ b_r,
                                float* __restrict__ out)
{
  int b = threadIdx.x;
  float bo = b_out[0], wr = w_r[0], br = b_r[0];
  float o = 0.f;
  for (int t = 0; t < T_SEQ; ++t){
    float pre = z[(size_t)t * NB + b] + bo;
    if (t > 0) pre += wr * o + br;
    o = 1.0f / (1.0f + __expf(-pre));
    out[(size_t)b * T_SEQ + t] = o;
  }
}

extern "C" void kernel_launch(void* const* d_in, const int* in_sizes, int n_in,
                              void* d_out, int out_size, void* d_ws, size_t ws_size,
                              hipStream_t stream)
{
  (void)in_sizes; (void)n_in; (void)out_size; (void)ws_size;
  const float* x     = (const float*)d_in[0];
  const float* W_ih  = (const float*)d_in[1];
  const float* b_ih  = (const float*)d_in[2];
  const float* W_hh  = (const float*)d_in[3];
  const float* b_hh  = (const float*)d_in[4];
  const float* W_out = (const float*)d_in[5];
  const float* b_out = (const float*)d_in[6];
  const float* w_r   = (const float*)d_in[7];
  const float* b_r   = (const float*)d_in[8];
  float* out = (float*)d_out;

  // ws: h ping-pong (2 x 512 KB bf16) | z (512 KB fp32) | flags (4 KB)
  unsigned short* hbuf = (unsigned short*)d_ws;
  float* z = (float*)((char*)d_ws + 2 * (size_t)NB * NH * sizeof(unsigned short));
  unsigned int* bar = (unsigned int*)((char*)d_ws
                        + 2 * (size_t)NB * NH * sizeof(unsigned short)
                        + (size_t)T_SEQ * NB * sizeof(float));

  hipMemsetAsync(bar, 0, 16 * 64 * sizeof(unsigned int), stream);

  rnn_scan_kernel<<<dim3(256), dim3(256), 0, stream>>>(
      x, W_ih, b_ih, W_hh, b_hh, W_out, hbuf, z, bar);

  out_scan_kernel<<<dim3(1), dim3(256), 0, stream>>>(z, b_out, w_r, b_r, out);
}